// Round 12
// baseline (276.229 us; speedup 1.0000x reference)
//
#include <hip/hip_runtime.h>
#include <hip/hip_bf16.h>

typedef __attribute__((ext_vector_type(8))) short short8;
typedef __attribute__((ext_vector_type(4))) float floatx4;

#define K3   27
#define CIN  64
#define COUT 64
#define MT   4      // 16-row m-tiles per wave -> 64 rows/wave, 256 rows/block
#define GSL  2      // ko slices per LDS group (2 x 16 KB double buffer)
#define NGRP 14     // 13 full groups of 2 + final group of 1

// f32 -> bf16 bits, round-to-nearest-even
static __device__ __forceinline__ short bf16bits(float x) {
    unsigned u = __builtin_bit_cast(unsigned, x);
    u += 0x7FFFu + ((u >> 16) & 1u);
    return (short)(u >> 16);
}

// async global->LDS, 16B per lane. lptr is wave-uniform base; HW adds lane*16.
static __device__ __forceinline__ void async16(const void* g, void* l) {
    __builtin_amdgcn_global_load_lds(
        (const __attribute__((address_space(1))) unsigned*)g,
        (__attribute__((address_space(3))) unsigned*)l, 16, 0, 0);
}

__global__ void write_sentinel(float* out, float v) {
    if (threadIdx.x == 0 && blockIdx.x == 0) out[0] = v;
}

// ---- fused prep ----
// roles: [0,27) weight->wt3 frag order; [27,27+tblk) idx->idxT[27][Mpad];
//        rest: features f32->bf16.
__global__ __launch_bounds__(256)
void prep_all(const float* __restrict__ feat, const float* __restrict__ w,
              const int* __restrict__ idx,
              short* __restrict__ featb, short* __restrict__ wt3,
              int* __restrict__ idxT,
              int n8, int M, int Mpad, int tblk) {
    const int t = threadIdx.x;
    if (blockIdx.x < K3) {
        __shared__ short tile[64][65];   // [cin][cout]
        const int ko = blockIdx.x;
#pragma unroll
        for (int i = 0; i < 16; ++i) {
            int e = t + i * 256;
            tile[e >> 6][e & 63] = bf16bits(w[(size_t)ko * 4096 + e]);
        }
        __syncthreads();
        const int cout = t & 63, s = t >> 6;
#pragma unroll
        for (int hh = 0; hh < 2; ++hh) {
            int s2 = s + hh * 4, kc = s2 >> 2, q = s2 & 3;
            short8 v;
#pragma unroll
            for (int j = 0; j < 8; ++j) v[j] = tile[kc * 32 + q * 8 + j][cout];
            ((short8*)wt3)[(size_t)ko * 512 + s2 * 64 + cout] = v;
        }
    } else if (blockIdx.x < K3 + tblk) {
        __shared__ int itile[256 * K3];  // 27648 B
        const int r0 = (blockIdx.x - K3) * 256;
#pragma unroll
        for (int i = 0; i < K3; ++i) {
            int flat = i * 256 + t;
            int grow = r0 + flat / K3;
            itile[flat] = (grow < M) ? idx[(size_t)r0 * K3 + flat] : -1;
        }
        __syncthreads();
#pragma unroll
        for (int j = 0; j < K3; ++j)
            idxT[(size_t)j * Mpad + r0 + t] = itile[t * K3 + j];
    } else {
        int i = (blockIdx.x - K3 - tblk) * 256 + t;
        if (i < n8) {
            const floatx4* src = (const floatx4*)feat + (size_t)i * 2;
            floatx4 v0 = src[0], v1 = src[1];
            short8 o;
            o[0] = bf16bits(v0.x); o[1] = bf16bits(v0.y);
            o[2] = bf16bits(v0.z); o[3] = bf16bits(v0.w);
            o[4] = bf16bits(v1.x); o[5] = bf16bits(v1.y);
            o[6] = bf16bits(v1.z); o[7] = bf16bits(v1.w);
            ((short8*)featb)[i] = o;
        }
    }
}

// ---- main: 256 rows/block (4 waves x 4 m-tiles), 16x16x32 MFMA,
// B via LDS dbuf staged with global_load_lds, idx via transposed idxT
// (1 sector per 16 rows), A-gather 2-deep ring. ----
__global__ __launch_bounds__(256, 3)
void spconv_mfma7(const short* __restrict__ featb,
                  const int* __restrict__ idxT,
                  const short* __restrict__ wt3,
                  float* __restrict__ out, int M, int Mpad) {
    __shared__ short lds[2][GSL * 4096];    // 2 x 16 KB
    const int tid = threadIdx.x, lane = tid & 63, wave = tid >> 6;
    const int wavebase = blockIdx.x * 256 + wave * 64;
    const int c = lane & 15, q = lane >> 4;

    const char* wtb = (const char*)wt3;

    // idx loads: per (ko, mt) one broadcast dword (quad-uniform address)
#define LOADIDX(KO, NB) do {                                            \
        const int* _p = idxT + (size_t)(KO) * Mpad + wavebase + c;      \
        NB[0] = _p[0]; NB[1] = _p[16]; NB[2] = _p[32]; NB[3] = _p[48];  \
    } while (0)

    // A-gather for one ko into 4 m-tile fragments (2 short8 each)
#define GATHER(NB, A) do {                                              \
        _Pragma("unroll")                                               \
        for (int mt = 0; mt < MT; ++mt) {                               \
            int _n = NB[mt];                                            \
            A[mt][0] = (short8)0; A[mt][1] = (short8)0;                 \
            if (_n >= 0) {                                              \
                const short8* _f = (const short8*)(featb + (size_t)_n * CIN); \
                A[mt][0] = _f[q]; A[mt][1] = _f[q + 4];                 \
            }                                                           \
        } } while (0)

    // --- prologue ---
    // DMA group 0 -> buf0
    {
        void* ldst = (void*)(lds[0] + wave * 512);           // +lane*16B by HW
#pragma unroll
        for (int i = 0; i < 4; ++i)
            async16(wtb + i * 4096 + wave * 1024 + (lane << 4),
                    (char*)ldst + i * 4096);
    }

    int    nbr[2][MT];
    short8 A[2][MT][2];
    LOADIDX(0, nbr[0]);
    LOADIDX(1, nbr[1]);
    GATHER(nbr[0], A[0]);
    GATHER(nbr[1], A[1]);
    LOADIDX(2, nbr[0]);
    LOADIDX(3, nbr[1]);

    floatx4 acc[MT][4];
#pragma unroll
    for (int mt = 0; mt < MT; ++mt)
#pragma unroll
        for (int nt = 0; nt < 4; ++nt) acc[mt][nt] = (floatx4)(0.0f);

    __syncthreads();   // buf0 ready (vmcnt drained)

#pragma unroll
    for (int g = 0; g < NGRP; ++g) {
        // issue DMA for group g+1 into the buffer freed by the last barrier
        if (g + 1 < NGRP) {
            const int ninstr = (g + 1 == NGRP - 1) ? 2 : 4;  // last group = 1 slice
            const char* src = wtb + (size_t)(g + 1) * 16384 + wave * 1024 + (lane << 4);
            void* ldst = (void*)(lds[(g + 1) & 1] + wave * 512);
#pragma unroll
            for (int i = 0; i < 4; ++i)
                if (i < ninstr)
                    async16(src + i * 4096, (char*)ldst + i * 4096);
        }
        const short8* B = (const short8*)lds[g & 1];
        const int jend = (g == NGRP - 1) ? 1 : GSL;
#pragma unroll
        for (int j = 0; j < GSL; ++j) {
            if (j >= jend) break;
            const int ko = g * GSL + j;
            const int cb = ko & 1;
#pragma unroll
            for (int nt = 0; nt < 4; ++nt) {
                short8 b0 = B[j * 512 + q * 64       + nt * 16 + c];  // kc=0
                short8 b1 = B[j * 512 + (4 + q) * 64 + nt * 16 + c];  // kc=1
#pragma unroll
                for (int mt = 0; mt < MT; ++mt) {
                    acc[mt][nt] = __builtin_amdgcn_mfma_f32_16x16x32_bf16(
                        A[cb][mt][0], b0, acc[mt][nt], 0, 0, 0);
                    acc[mt][nt] = __builtin_amdgcn_mfma_f32_16x16x32_bf16(
                        A[cb][mt][1], b1, acc[mt][nt], 0, 0, 0);
                }
            }
            // refill: gather ko+2 (idx loaded 2 iters ago), load idx ko+4
            if (ko + 2 < K3) GATHER(nbr[cb], A[cb]);
            if (ko + 4 < K3) LOADIDX(ko + 4, nbr[cb]);
        }
        __syncthreads();
    }
#undef GATHER
#undef LOADIDX

    // C/D layout: col = lane&15, row = q*4 + reg
#pragma unroll
    for (int mt = 0; mt < MT; ++mt) {
#pragma unroll
        for (int r = 0; r < 4; ++r) {
            int row = wavebase + mt * 16 + q * 4 + r;
            if (row < M) {
                float* o = out + (size_t)row * COUT;
#pragma unroll
                for (int nt = 0; nt < 4; ++nt)
                    o[nt * 16 + c] = acc[mt][nt][r];
            }
        }
    }
}

// ---------- fallback (round-6 proven path, used if ws too small) ----------
__global__ void transpose_weight(const float* __restrict__ w,
                                 __hip_bfloat16* __restrict__ wt) {
    __shared__ short tile[64][65];
    const int k = blockIdx.x;
    const float* src = w + k * (CIN * COUT);
    short* dst = (short*)(wt + k * (CIN * COUT));
    const int t = threadIdx.x;
#pragma unroll
    for (int i = 0; i < 16; ++i) {
        int e = t + i * 256;
        tile[e >> 6][e & 63] = bf16bits(src[e]);
    }
    __syncthreads();
#pragma unroll
    for (int i = 0; i < 16; ++i) {
        int e = t + i * 256;
        dst[e] = tile[e & 63][e >> 6];
    }
}

__global__ __launch_bounds__(256, 4)
void spconv_mfma(const float* __restrict__ feat,
                 const int* __restrict__ idx,
                 const __hip_bfloat16* __restrict__ wt,
                 float* __restrict__ out,
                 int M, int N) {
    const int lane = threadIdx.x & 63;
    const int wave = threadIdx.x >> 6;
    const int m0   = blockIdx.x * 64 + wave * 16;
    const int c    = lane & 15;
    const int q    = lane >> 4;

    floatx4 acc[4];
#pragma unroll
    for (int nt = 0; nt < 4; ++nt) acc[nt] = (floatx4)(0.0f);

    const int  rowA  = m0 + c;
    const long ibase = (long)rowA * K3;

    for (int ko = 0; ko < K3; ++ko) {
        int nb = (rowA < M) ? idx[ibase + ko] : -1;
        short8 a0 = (short8)(0);
        short8 a1 = (short8)(0);
        if (nb >= 0 && nb < N) {
            const floatx4* f = (const floatx4*)(feat + (size_t)nb * CIN);
            floatx4 f0 = f[q * 2 + 0];
            floatx4 f1 = f[q * 2 + 1];
            floatx4 f2 = f[q * 2 + 8];
            floatx4 f3 = f[q * 2 + 9];
            a0[0] = bf16bits(f0.x); a0[1] = bf16bits(f0.y);
            a0[2] = bf16bits(f0.z); a0[3] = bf16bits(f0.w);
            a0[4] = bf16bits(f1.x); a0[5] = bf16bits(f1.y);
            a0[6] = bf16bits(f1.z); a0[7] = bf16bits(f1.w);
            a1[0] = bf16bits(f2.x); a1[1] = bf16bits(f2.y);
            a1[2] = bf16bits(f2.z); a1[3] = bf16bits(f2.w);
            a1[4] = bf16bits(f3.x); a1[5] = bf16bits(f3.y);
            a1[6] = bf16bits(f3.z); a1[7] = bf16bits(f3.w);
        }
        const short8* wr = (const short8*)(wt + ko * (CIN * COUT));
#pragma unroll
        for (int nt = 0; nt < 4; ++nt) {
            short8 b0 = wr[(nt * 16 + c) * 8 + q];
            short8 b1 = wr[(nt * 16 + c) * 8 + 4 + q];
            acc[nt] = __builtin_amdgcn_mfma_f32_16x16x32_bf16(a0, b0, acc[nt], 0, 0, 0);
            acc[nt] = __builtin_amdgcn_mfma_f32_16x16x32_bf16(a1, b1, acc[nt], 0, 0, 0);
        }
    }
#pragma unroll
    for (int r = 0; r < 4; ++r) {
        int row = m0 + q * 4 + r;
        if (row < M) {
            float* o = out + (size_t)row * COUT;
#pragma unroll
            for (int nt = 0; nt < 4; ++nt)
                o[nt * 16 + c] = acc[nt][r];
        }
    }
}

extern "C" void kernel_launch(void* const* d_in, const int* in_sizes, int n_in,
                              void* d_out, int out_size, void* d_ws, size_t ws_size,
                              hipStream_t stream) {
    float* out = (float*)d_out;

    float sentinel = 0.0f;
    if (n_in != 3)                                   sentinel = 1.0e6f;
    else if (in_sizes[2] != K3 * CIN * COUT)         sentinel = 2.0e6f;
    else if (in_sizes[1] % K3 != 0)                  sentinel = 3.0e6f;
    else if (in_sizes[1] / K3 != out_size / COUT)    sentinel = 4.0e6f;
    else if (in_sizes[0] % CIN != 0)                 sentinel = 5.0e6f;
    if (sentinel != 0.0f) {
        write_sentinel<<<1, 64, 0, stream>>>(out, sentinel);
        return;
    }

    const float* feat = (const float*)d_in[0];
    const int*   idx  = (const int*)d_in[1];
    const float* w    = (const float*)d_in[2];

    const int M = in_sizes[1] / K3;
    const int N = in_sizes[0] / CIN;

    const int grid = (M + 255) / 256;      // main blocks == transpose blocks
    const int Mpad = grid * 256;

    const size_t featb_bytes = (size_t)N * CIN * 2;
    const size_t wt_off  = (featb_bytes + 255) & ~(size_t)255;
    const size_t wt_bytes = (size_t)K3 * 512 * 16;
    const size_t it_off  = (wt_off + wt_bytes + 255) & ~(size_t)255;
    const size_t need    = it_off + (size_t)K3 * Mpad * 4;

    if (ws_size >= need) {
        short* featb = (short*)d_ws;
        short* wt3   = (short*)((char*)d_ws + wt_off);
        int*   idxT  = (int*)((char*)d_ws + it_off);
        const int n8 = N * CIN / 8;
        const int prep_grid = K3 + grid + (n8 + 255) / 256;
        prep_all<<<prep_grid, 256, 0, stream>>>(feat, w, idx, featb, wt3, idxT,
                                                n8, M, Mpad, grid);
        spconv_mfma7<<<grid, 256, 0, stream>>>(featb, idxT, wt3, out, M, Mpad);
    } else {
        __hip_bfloat16* wt = (__hip_bfloat16*)d_ws;
        transpose_weight<<<K3, 256, 0, stream>>>(w, wt);
        const int g2 = (M + 63) / 64;
        spconv_mfma<<<g2, 256, 0, stream>>>(feat, idx, wt, out, M, N);
    }
}

// Round 13
// 187.582 us; speedup vs baseline: 1.4726x; 1.4726x over previous
//
#include <hip/hip_runtime.h>
#include <hip/hip_bf16.h>

typedef __attribute__((ext_vector_type(8))) short short8;
typedef __attribute__((ext_vector_type(4))) float floatx4;

#define K3   27
#define CIN  64
#define COUT 64
#define MT   2      // 16-row m-tiles per wave -> 32 rows/wave, 128 rows/block

// f32 -> bf16 bits, round-to-nearest-even
static __device__ __forceinline__ short bf16bits(float x) {
    unsigned u = __builtin_bit_cast(unsigned, x);
    u += 0x7FFFu + ((u >> 16) & 1u);
    return (short)(u >> 16);
}

// async global->LDS, 16B per lane. LDS dest = wave-uniform base + lane*16.
static __device__ __forceinline__ void async16(const void* g, void* l) {
    __builtin_amdgcn_global_load_lds(
        (const __attribute__((address_space(1))) unsigned*)g,
        (__attribute__((address_space(3))) unsigned*)l, 16, 0, 0);
}

__global__ void write_sentinel(float* out, float v) {
    if (threadIdx.x == 0 && blockIdx.x == 0) out[0] = v;
}

// ---- fused prep (unchanged from round 12, proven correct) ----
// roles: [0,27) weight->wt3 frag order; [27,27+tblk) idx->idxT[27][Mpad];
//        rest: features f32->bf16.
__global__ __launch_bounds__(256)
void prep_all(const float* __restrict__ feat, const float* __restrict__ w,
              const int* __restrict__ idx,
              short* __restrict__ featb, short* __restrict__ wt3,
              int* __restrict__ idxT,
              int n8, int M, int Mpad, int tblk) {
    const int t = threadIdx.x;
    if (blockIdx.x < K3) {
        __shared__ short tile[64][65];   // [cin][cout]
        const int ko = blockIdx.x;
#pragma unroll
        for (int i = 0; i < 16; ++i) {
            int e = t + i * 256;
            tile[e >> 6][e & 63] = bf16bits(w[(size_t)ko * 4096 + e]);
        }
        __syncthreads();
        const int cout = t & 63, s = t >> 6;
#pragma unroll
        for (int hh = 0; hh < 2; ++hh) {
            int s2 = s + hh * 4, kc = s2 >> 2, q = s2 & 3;
            short8 v;
#pragma unroll
            for (int j = 0; j < 8; ++j) v[j] = tile[kc * 32 + q * 8 + j][cout];
            ((short8*)wt3)[(size_t)ko * 512 + s2 * 64 + cout] = v;
        }
    } else if (blockIdx.x < K3 + tblk) {
        __shared__ int itile[256 * K3];  // 27648 B
        const int r0 = (blockIdx.x - K3) * 256;
#pragma unroll
        for (int i = 0; i < K3; ++i) {
            int flat = i * 256 + t;
            int grow = r0 + flat / K3;
            itile[flat] = (grow < M) ? idx[(size_t)r0 * K3 + flat] : -1;
        }
        __syncthreads();
#pragma unroll
        for (int j = 0; j < K3; ++j)
            idxT[(size_t)j * Mpad + r0 + t] = itile[t * K3 + j];
    } else {
        int i = (blockIdx.x - K3 - tblk) * 256 + t;
        if (i < n8) {
            const floatx4* src = (const floatx4*)feat + (size_t)i * 2;
            floatx4 v0 = src[0], v1 = src[1];
            short8 o;
            o[0] = bf16bits(v0.x); o[1] = bf16bits(v0.y);
            o[2] = bf16bits(v0.z); o[3] = bf16bits(v0.w);
            o[4] = bf16bits(v1.x); o[5] = bf16bits(v1.y);
            o[6] = bf16bits(v1.z); o[7] = bf16bits(v1.w);
            ((short8*)featb)[i] = o;
        }
    }
}

// ---- main: 128 rows/block (4 waves x 2 m-tiles), 16x16x32 MFMA.
// B: 2 x 8KB LDS dbuf staged via global_load_lds (no staging regs).
// idx: broadcast loads from idxT (1-2 lines per wave*ko).
// A: register ring depth 2, exec-masked gather (requests only for valid). ----
__global__ __launch_bounds__(256, 4)
void spconv_mfma8(const short* __restrict__ featb,
                  const int* __restrict__ idxT,
                  const short* __restrict__ wt3,
                  float* __restrict__ out, int M, int Mpad) {
    __shared__ short lds[2][4096];          // 2 x 8 KB
    const int tid = threadIdx.x, lane = tid & 63, wave = tid >> 6;
    const int wavebase = blockIdx.x * 128 + wave * 32;
    const int c = lane & 15, q = lane >> 4;

    const char* wtb = (const char*)wt3;

    // B-DMA of one ko slice (8 KB): wave w issues chunks w and w+4 (1 KB each)
#define STAGE_B(KO, BUF) do {                                               \
        const char* _s = wtb + (size_t)(KO) * 8192 + (lane << 4);           \
        char* _d = (char*)lds[BUF];                                         \
        async16(_s + wave * 1024,        _d + wave * 1024);                 \
        async16(_s + (wave + 4) * 1024,  _d + (wave + 4) * 1024);           \
    } while (0)

    // idx loads: rows wavebase+c (mt0) and wavebase+16+c (mt1), broadcast
#define LOADIDX(KO, NB) do {                                                \
        const int* _p = idxT + (size_t)(KO) * Mpad + wavebase + c;          \
        NB[0] = _p[0]; NB[1] = _p[16];                                      \
    } while (0)

    // exec-masked gather of one ko into 2 m-tile fragments (2 short8 each)
#define GATHER(NB, A) do {                                                  \
        _Pragma("unroll")                                                   \
        for (int mt = 0; mt < MT; ++mt) {                                   \
            int _n = NB[mt];                                                \
            A[mt][0] = (short8)0; A[mt][1] = (short8)0;                     \
            if (_n >= 0) {                                                  \
                const short8* _f = (const short8*)(featb + (size_t)_n * CIN); \
                A[mt][0] = _f[q]; A[mt][1] = _f[q + 4];                     \
            }                                                               \
        } } while (0)

    // --- prologue ---
    STAGE_B(0, 0);

    int    nbr[2][MT];
    short8 A[2][MT][2];
    LOADIDX(0, nbr[0]);
    LOADIDX(1, nbr[1]);
    GATHER(nbr[0], A[0]);
    GATHER(nbr[1], A[1]);
    LOADIDX(2, nbr[0]);
    LOADIDX(3, nbr[1]);

    floatx4 acc[MT][4];
#pragma unroll
    for (int mt = 0; mt < MT; ++mt)
#pragma unroll
        for (int nt = 0; nt < 4; ++nt) acc[mt][nt] = (floatx4)(0.0f);

    __syncthreads();   // buf0 DMA drained

#pragma unroll
    for (int ko = 0; ko < K3; ++ko) {
        const int cb = ko & 1;
        if (ko + 1 < K3) STAGE_B(ko + 1, (ko + 1) & 1);
        const short8* B = (const short8*)lds[cb];
#pragma unroll
        for (int nt = 0; nt < 4; ++nt) {
            short8 b0 = B[q * 64       + nt * 16 + c];   // kc = 0
            short8 b1 = B[(4 + q) * 64 + nt * 16 + c];   // kc = 1
#pragma unroll
            for (int mt = 0; mt < MT; ++mt) {
                acc[mt][nt] = __builtin_amdgcn_mfma_f32_16x16x32_bf16(
                    A[cb][mt][0], b0, acc[mt][nt], 0, 0, 0);
                acc[mt][nt] = __builtin_amdgcn_mfma_f32_16x16x32_bf16(
                    A[cb][mt][1], b1, acc[mt][nt], 0, 0, 0);
            }
        }
        // refill ring: gather ko+2 (idx loaded 2 iters ago), idx for ko+4
        if (ko + 2 < K3) GATHER(nbr[cb], A[cb]);
        if (ko + 4 < K3) LOADIDX(ko + 4, nbr[cb]);
        __syncthreads();
    }
#undef GATHER
#undef LOADIDX
#undef STAGE_B

    // C/D layout: col = lane&15, row = q*4 + reg
#pragma unroll
    for (int mt = 0; mt < MT; ++mt) {
#pragma unroll
        for (int r = 0; r < 4; ++r) {
            int row = wavebase + mt * 16 + q * 4 + r;
            if (row < M) {
                float* o = out + (size_t)row * COUT;
#pragma unroll
                for (int nt = 0; nt < 4; ++nt)
                    o[nt * 16 + c] = acc[mt][nt][r];
            }
        }
    }
}

// ---------- fallback (round-6 proven path, used if ws too small) ----------
__global__ void transpose_weight(const float* __restrict__ w,
                                 __hip_bfloat16* __restrict__ wt) {
    __shared__ short tile[64][65];
    const int k = blockIdx.x;
    const float* src = w + k * (CIN * COUT);
    short* dst = (short*)(wt + k * (CIN * COUT));
    const int t = threadIdx.x;
#pragma unroll
    for (int i = 0; i < 16; ++i) {
        int e = t + i * 256;
        tile[e >> 6][e & 63] = bf16bits(src[e]);
    }
    __syncthreads();
#pragma unroll
    for (int i = 0; i < 16; ++i) {
        int e = t + i * 256;
        dst[e] = tile[e & 63][e >> 6];
    }
}

__global__ __launch_bounds__(256, 4)
void spconv_mfma(const float* __restrict__ feat,
                 const int* __restrict__ idx,
                 const __hip_bfloat16* __restrict__ wt,
                 float* __restrict__ out,
                 int M, int N) {
    const int lane = threadIdx.x & 63;
    const int wave = threadIdx.x >> 6;
    const int m0   = blockIdx.x * 64 + wave * 16;
    const int c    = lane & 15;
    const int q    = lane >> 4;

    floatx4 acc[4];
#pragma unroll
    for (int nt = 0; nt < 4; ++nt) acc[nt] = (floatx4)(0.0f);

    const int  rowA  = m0 + c;
    const long ibase = (long)rowA * K3;

    for (int ko = 0; ko < K3; ++ko) {
        int nb = (rowA < M) ? idx[ibase + ko] : -1;
        short8 a0 = (short8)(0);
        short8 a1 = (short8)(0);
        if (nb >= 0 && nb < N) {
            const floatx4* f = (const floatx4*)(feat + (size_t)nb * CIN);
            floatx4 f0 = f[q * 2 + 0];
            floatx4 f1 = f[q * 2 + 1];
            floatx4 f2 = f[q * 2 + 8];
            floatx4 f3 = f[q * 2 + 9];
            a0[0] = bf16bits(f0.x); a0[1] = bf16bits(f0.y);
            a0[2] = bf16bits(f0.z); a0[3] = bf16bits(f0.w);
            a0[4] = bf16bits(f1.x); a0[5] = bf16bits(f1.y);
            a0[6] = bf16bits(f1.z); a0[7] = bf16bits(f1.w);
            a1[0] = bf16bits(f2.x); a1[1] = bf16bits(f2.y);
            a1[2] = bf16bits(f2.z); a1[3] = bf16bits(f2.w);
            a1[4] = bf16bits(f3.x); a1[5] = bf16bits(f3.y);
            a1[6] = bf16bits(f3.z); a1[7] = bf16bits(f3.w);
        }
        const short8* wr = (const short8*)(wt + ko * (CIN * COUT));
#pragma unroll
        for (int nt = 0; nt < 4; ++nt) {
            short8 b0 = wr[(nt * 16 + c) * 8 + q];
            short8 b1 = wr[(nt * 16 + c) * 8 + 4 + q];
            acc[nt] = __builtin_amdgcn_mfma_f32_16x16x32_bf16(a0, b0, acc[nt], 0, 0, 0);
            acc[nt] = __builtin_amdgcn_mfma_f32_16x16x32_bf16(a1, b1, acc[nt], 0, 0, 0);
        }
    }
#pragma unroll
    for (int r = 0; r < 4; ++r) {
        int row = m0 + q * 4 + r;
        if (row < M) {
            float* o = out + (size_t)row * COUT;
#pragma unroll
            for (int nt = 0; nt < 4; ++nt)
                o[nt * 16 + c] = acc[nt][r];
        }
    }
}

extern "C" void kernel_launch(void* const* d_in, const int* in_sizes, int n_in,
                              void* d_out, int out_size, void* d_ws, size_t ws_size,
                              hipStream_t stream) {
    float* out = (float*)d_out;

    float sentinel = 0.0f;
    if (n_in != 3)                                   sentinel = 1.0e6f;
    else if (in_sizes[2] != K3 * CIN * COUT)         sentinel = 2.0e6f;
    else if (in_sizes[1] % K3 != 0)                  sentinel = 3.0e6f;
    else if (in_sizes[1] / K3 != out_size / COUT)    sentinel = 4.0e6f;
    else if (in_sizes[0] % CIN != 0)                 sentinel = 5.0e6f;
    if (sentinel != 0.0f) {
        write_sentinel<<<1, 64, 0, stream>>>(out, sentinel);
        return;
    }

    const float* feat = (const float*)d_in[0];
    const int*   idx  = (const int*)d_in[1];
    const float* w    = (const float*)d_in[2];

    const int M = in_sizes[1] / K3;
    const int N = in_sizes[0] / CIN;

    const int tblk = (M + 255) / 256;      // idx-transpose blocks (256 rows each)
    const int Mpad = tblk * 256;
    const int grid = (M + 127) / 128;      // main blocks (128 rows each)

    const size_t featb_bytes = (size_t)N * CIN * 2;
    const size_t wt_off   = (featb_bytes + 255) & ~(size_t)255;
    const size_t wt_bytes = (size_t)K3 * 512 * 16;
    const size_t it_off   = (wt_off + wt_bytes + 255) & ~(size_t)255;
    const size_t need     = it_off + (size_t)K3 * Mpad * 4;

    if (ws_size >= need) {
        short* featb = (short*)d_ws;
        short* wt3   = (short*)((char*)d_ws + wt_off);
        int*   idxT  = (int*)((char*)d_ws + it_off);
        const int n8 = N * CIN / 8;
        const int prep_grid = K3 + tblk + (n8 + 255) / 256;
        prep_all<<<prep_grid, 256, 0, stream>>>(feat, w, idx, featb, wt3, idxT,
                                                n8, M, Mpad, tblk);
        spconv_mfma8<<<grid, 256, 0, stream>>>(featb, idxT, wt3, out, M, Mpad);
    } else {
        __hip_bfloat16* wt = (__hip_bfloat16*)d_ws;
        transpose_weight<<<K3, 256, 0, stream>>>(w, wt);
        const int g2 = (M + 63) / 64;
        spconv_mfma<<<g2, 256, 0, stream>>>(feat, idx, wt, out, M, N);
    }
}